// Round 1
// baseline (781.848 us; speedup 1.0000x reference)
//
#include <hip/hip_runtime.h>
#include <cstdint>
#include <cstddef>

typedef _Float16 half_t;
typedef _Float16 half8 __attribute__((ext_vector_type(8)));
typedef _Float16 half4_t __attribute__((ext_vector_type(4)));
typedef float f32x4 __attribute__((ext_vector_type(4)));

#define HIDDEN 512
#define NHEADS 8
#define HDIM 64
#define NB 8
#define NSEQ 512
#define NROWS (NB * NSEQ) /* 4096 */
#define TLD 40            /* LDS tile leading dim (halves): 32 + 8 pad to break bank conflicts */

// ---------------------------------------------------------------------------
// fp32 -> f16 convert (x)
// ---------------------------------------------------------------------------
__global__ __launch_bounds__(256) void conv_x_kernel(const float* __restrict__ x,
                                                     half_t* __restrict__ xh) {
  int i = (blockIdx.x * 256 + threadIdx.x) * 4;
  f32x4 v = *(const f32x4*)(x + i);
  half4_t h;
  h[0] = (half_t)v[0]; h[1] = (half_t)v[1]; h[2] = (half_t)v[2]; h[3] = (half_t)v[3];
  *(half4_t*)(xh + i) = h;
}

// ---------------------------------------------------------------------------
// transpose + convert the four 512x512 weights: WT[n][k] = W[k][n], f16 out
// ---------------------------------------------------------------------------
__global__ __launch_bounds__(256) void conv_wt_kernel(
    const float* __restrict__ Wq, const float* __restrict__ Wk,
    const float* __restrict__ Wv, const float* __restrict__ Wo,
    half_t* __restrict__ WqT, half_t* __restrict__ WkT,
    half_t* __restrict__ WvT, half_t* __restrict__ WoT) {
  const float* src; half_t* dst;
  switch (blockIdx.z) {
    case 0: src = Wq; dst = WqT; break;
    case 1: src = Wk; dst = WkT; break;
    case 2: src = Wv; dst = WvT; break;
    default: src = Wo; dst = WoT; break;
  }
  __shared__ float tile[64][65];
  int r0 = blockIdx.y * 64, c0 = blockIdx.x * 64;
#pragma unroll
  for (int i = 0; i < 16; i++) {
    int idx = threadIdx.x + i * 256;
    int r = idx >> 6, c = idx & 63;
    tile[r][c] = src[(size_t)(r0 + r) * HIDDEN + c0 + c];
  }
  __syncthreads();
#pragma unroll
  for (int i = 0; i < 16; i++) {
    int idx = threadIdx.x + i * 256;
    int r = idx >> 6, c = idx & 63;
    dst[(size_t)(c0 + r) * HIDDEN + r0 + c] = (half_t)tile[c][r];
  }
}

// ---------------------------------------------------------------------------
// MFMA GEMM core: C[128,128] = A[128,K] @ Bt[128,K]^T, f16 in, fp32 acc
// Tile: BK=32, 4 waves in 2x2, each wave 64x64 via 4x4 frags of 16x16x32.
// ---------------------------------------------------------------------------
__device__ __forceinline__ void stage128x32(const half_t* __restrict__ G, int ldg,
                                            int t, half_t* Ls) {
#pragma unroll
  for (int p = 0; p < 2; p++) {
    int v = t + p * 256;        // 0..511
    int row = v >> 2, col = (v & 3) * 8;
    *(uint4*)(Ls + row * TLD + col) = *(const uint4*)(G + (size_t)row * ldg + col);
  }
}

__device__ __forceinline__ void stage64x32(const half_t* __restrict__ G, int ldg,
                                           int t, half_t* Ls) {
  int row = t >> 2, col = (t & 3) * 8;
  *(uint4*)(Ls + row * TLD + col) = *(const uint4*)(G + (size_t)row * ldg + col);
}

__device__ __forceinline__ void gemm_core_128x128(
    const half_t* __restrict__ A, int lda, const half_t* __restrict__ Bt, int ldbt,
    int Kdim, half_t* As, half_t* Bs, f32x4 acc[4][4]) {
  int t = threadIdx.x;
  int lane = t & 63, wave = t >> 6;
  int quad = lane >> 4, r16 = lane & 15;
  int m0 = (wave & 1) * 64, n0 = (wave >> 1) * 64;
#pragma unroll
  for (int mi = 0; mi < 4; mi++)
#pragma unroll
    for (int ni = 0; ni < 4; ni++) acc[mi][ni] = (f32x4){0.f, 0.f, 0.f, 0.f};
  for (int k0 = 0; k0 < Kdim; k0 += 32) {
    __syncthreads();
    stage128x32(A + k0, lda, t, As);
    stage128x32(Bt + k0, ldbt, t, Bs);
    __syncthreads();
    half8 af[4], bf[4];
#pragma unroll
    for (int mi = 0; mi < 4; mi++)
      af[mi] = *(const half8*)(As + (m0 + mi * 16 + r16) * TLD + quad * 8);
#pragma unroll
    for (int ni = 0; ni < 4; ni++)
      bf[ni] = *(const half8*)(Bs + (n0 + ni * 16 + r16) * TLD + quad * 8);
#pragma unroll
    for (int mi = 0; mi < 4; mi++)
#pragma unroll
      for (int ni = 0; ni < 4; ni++)
        acc[mi][ni] = __builtin_amdgcn_mfma_f32_16x16x32_f16(af[mi], bf[ni], acc[mi][ni], 0, 0, 0);
  }
}

// ---------------------------------------------------------------------------
// K1: QKV projection. z=0:Q, z=1:K (plain [4096,512] f16), z=2:V (transposed
// into Vt[b,h,d,n] so it serves as B^T for the PV GEMM).
// ---------------------------------------------------------------------------
__global__ __launch_bounds__(256) void gemm_qkv_kernel(
    const half_t* __restrict__ xh,
    const half_t* __restrict__ WqT, const half_t* __restrict__ WkT, const half_t* __restrict__ WvT,
    const float* __restrict__ bq, const float* __restrict__ bk, const float* __restrict__ bv,
    half_t* __restrict__ Qh, half_t* __restrict__ Kh, half_t* __restrict__ Vt) {
  __shared__ half_t As[128 * TLD];
  __shared__ half_t Bs[128 * TLD];
  int z = blockIdx.z;
  const half_t* W = (z == 0) ? WqT : ((z == 1) ? WkT : WvT);
  const float* bias = (z == 0) ? bq : ((z == 1) ? bk : bv);
  int row0 = blockIdx.x * 128, col0 = blockIdx.y * 128;
  f32x4 acc[4][4];
  gemm_core_128x128(xh + (size_t)row0 * HIDDEN, HIDDEN, W + (size_t)col0 * HIDDEN, HIDDEN,
                    HIDDEN, As, Bs, acc);
  int lane = threadIdx.x & 63, wave = threadIdx.x >> 6;
  int quad = lane >> 4, r16 = lane & 15;
  int m0 = (wave & 1) * 64, n0 = (wave >> 1) * 64;
#pragma unroll
  for (int mi = 0; mi < 4; mi++)
#pragma unroll
    for (int ni = 0; ni < 4; ni++) {
      int gcol = col0 + n0 + ni * 16 + r16;
      float bb = bias[gcol];
#pragma unroll
      for (int reg = 0; reg < 4; reg++) {
        int grow = row0 + m0 + mi * 16 + quad * 4 + reg;
        float v = acc[mi][ni][reg] + bb;
        if (z == 0) {
          Qh[(size_t)grow * HIDDEN + gcol] = (half_t)v;
        } else if (z == 1) {
          Kh[(size_t)grow * HIDDEN + gcol] = (half_t)v;
        } else {
          int b = grow >> 9, nn = grow & 511, h = gcol >> 6, d = gcol & 63;
          Vt[((size_t)(b * NHEADS + h) * HDIM + d) * NSEQ + nn] = (half_t)v;
        }
      }
    }
}

// ---------------------------------------------------------------------------
// K2: scores S[b,h,q,k] = (Q . K)/8, f16 out. Per (b,h): M=N=512, K=64.
// ---------------------------------------------------------------------------
__global__ __launch_bounds__(256) void gemm_scores_kernel(
    const half_t* __restrict__ Qh, const half_t* __restrict__ Kh, half_t* __restrict__ S) {
  __shared__ half_t As[128 * TLD];
  __shared__ half_t Bs[128 * TLD];
  int bh = blockIdx.z;
  int b = bh >> 3, h = bh & 7;
  int q0 = blockIdx.x * 128, kc0 = blockIdx.y * 128;
  const half_t* A = Qh + ((size_t)(b * NSEQ) + q0) * HIDDEN + h * HDIM;
  const half_t* Bt = Kh + ((size_t)(b * NSEQ) + kc0) * HIDDEN + h * HDIM;
  f32x4 acc[4][4];
  gemm_core_128x128(A, HIDDEN, Bt, HIDDEN, HDIM, As, Bs, acc);
  int lane = threadIdx.x & 63, wave = threadIdx.x >> 6;
  int quad = lane >> 4, r16 = lane & 15;
  int m0 = (wave & 1) * 64, n0 = (wave >> 1) * 64;
#pragma unroll
  for (int mi = 0; mi < 4; mi++)
#pragma unroll
    for (int ni = 0; ni < 4; ni++) {
      int kk = kc0 + n0 + ni * 16 + r16;
#pragma unroll
      for (int reg = 0; reg < 4; reg++) {
        int q = q0 + m0 + mi * 16 + quad * 4 + reg;
        S[((size_t)bh * NSEQ + q) * NSEQ + kk] = (half_t)(acc[mi][ni][reg] * 0.125f);
      }
    }
}

// ---------------------------------------------------------------------------
// K3: per (b,q): bias = dist[b,q,:,:] @ Wd + bd via MFMA (M=512 keys, N=16
// (8 heads used), K=64); add to S, key-mask, softmax over k, write P in-place.
// This kernel carries the 512 MiB dist stream -> it is the HBM-bound phase.
// ---------------------------------------------------------------------------
__global__ __launch_bounds__(256) void bias_softmax_kernel(
    const float* __restrict__ dist, const float* __restrict__ Wd,
    const float* __restrict__ bd, const int* __restrict__ mask,
    half_t* __restrict__ S) {
  __shared__ float sc[8 * 520];  // [8 heads][512 keys], stride 520 vs bank conflicts
  int q = blockIdx.x, b = blockIdx.y;
  int t = threadIdx.x, lane = t & 63, wave = t >> 6;
  int quad = lane >> 4, r16 = lane & 15;

  // B-fragment: Bt[n=head][kd] = Wd[kd][head], zero-padded heads 8..15
  half8 bfrag[2];
#pragma unroll
  for (int f = 0; f < 2; f++)
#pragma unroll
    for (int j = 0; j < 8; j++) {
      int d = f * 32 + quad * 8 + j;
      bfrag[f][j] = (r16 < 8) ? (half_t)Wd[d * 8 + r16] : (half_t)0.f;
    }

  const float* dbase = dist + ((size_t)(b * NSEQ + q)) * NSEQ * HDIM;
  const int* mrow = mask + b * NSEQ;

  for (int mt = 0; mt < 8; mt++) {
    int k0 = wave * 128 + mt * 16;
    const float* dp = dbase + (size_t)(k0 + r16) * HDIM;
    f32x4 acc = (f32x4){0.f, 0.f, 0.f, 0.f};
#pragma unroll
    for (int f = 0; f < 2; f++) {
      f32x4 v0 = *(const f32x4*)(dp + f * 32 + quad * 8);
      f32x4 v1 = *(const f32x4*)(dp + f * 32 + quad * 8 + 4);
      half8 af;
      af[0] = (half_t)v0[0]; af[1] = (half_t)v0[1]; af[2] = (half_t)v0[2]; af[3] = (half_t)v0[3];
      af[4] = (half_t)v1[0]; af[5] = (half_t)v1[1]; af[6] = (half_t)v1[2]; af[7] = (half_t)v1[3];
      acc = __builtin_amdgcn_mfma_f32_16x16x32_f16(af, bfrag[f], acc, 0, 0, 0);
    }
    if (r16 < 8) {
      int h = r16;
      int kq = k0 + quad * 4;
      half4_t sv = *(const half4_t*)(S + ((size_t)(b * NHEADS + h) * NSEQ + q) * NSEQ + kq);
      int4 mk = *(const int4*)(mrow + kq);
      float bdh = bd[h];
#pragma unroll
      for (int reg = 0; reg < 4; reg++) {
        float v = (float)sv[reg] + acc[reg] + bdh;
        int mval = (reg == 0) ? mk.x : ((reg == 1) ? mk.y : ((reg == 2) ? mk.z : mk.w));
        sc[h * 520 + kq + reg] = mval ? v : -1e9f;
      }
    }
  }
  __syncthreads();

  // softmax per head: wave handles heads {wave, wave+4}; 8 values per lane
  for (int h = wave; h < 8; h += 4) {
    float vals[8];
    float m = -3.4e38f;
#pragma unroll
    for (int i = 0; i < 8; i++) {
      vals[i] = sc[h * 520 + i * 64 + lane];
      m = fmaxf(m, vals[i]);
    }
#pragma unroll
    for (int off = 32; off >= 1; off >>= 1) m = fmaxf(m, __shfl_xor(m, off));
    float s = 0.f;
#pragma unroll
    for (int i = 0; i < 8; i++) {
      vals[i] = __expf(vals[i] - m);
      s += vals[i];
    }
#pragma unroll
    for (int off = 32; off >= 1; off >>= 1) s += __shfl_xor(s, off);
    float inv = 1.f / s;
    half_t* P = S + ((size_t)(b * NHEADS + h) * NSEQ + q) * NSEQ;
#pragma unroll
    for (int i = 0; i < 8; i++) P[i * 64 + lane] = (half_t)(vals[i] * inv);
  }
}

// ---------------------------------------------------------------------------
// K4: O = P @ V per (b,h): M=512, N=64, K=512. Tile 128x64; 4 waves stacked
// in M (each 32x64 via 2x4 frags). Bt = Vt[b,h] (already [d,k]).
// Output into AO[b, n, h*64+d] (row-major hidden) for the final projection.
// ---------------------------------------------------------------------------
__global__ __launch_bounds__(256) void gemm_pv_kernel(
    const half_t* __restrict__ P, const half_t* __restrict__ Vt, half_t* __restrict__ AO) {
  __shared__ half_t As[128 * TLD];
  __shared__ half_t Bs[64 * TLD];
  int bh = blockIdx.z, b = bh >> 3, h = bh & 7;
  int q0 = blockIdx.x * 128;
  const half_t* A = P + ((size_t)bh * NSEQ + q0) * NSEQ;
  const half_t* Bt = Vt + (size_t)bh * HDIM * NSEQ;
  int t = threadIdx.x, lane = t & 63, wave = t >> 6;
  int quad = lane >> 4, r16 = lane & 15;
  int m0 = wave * 32;
  f32x4 acc[2][4];
#pragma unroll
  for (int mi = 0; mi < 2; mi++)
#pragma unroll
    for (int ni = 0; ni < 4; ni++) acc[mi][ni] = (f32x4){0.f, 0.f, 0.f, 0.f};
  for (int k0 = 0; k0 < NSEQ; k0 += 32) {
    __syncthreads();
    stage128x32(A + k0, NSEQ, t, As);
    stage64x32(Bt + k0, NSEQ, t, Bs);
    __syncthreads();
    half8 af[2], bf[4];
#pragma unroll
    for (int mi = 0; mi < 2; mi++)
      af[mi] = *(const half8*)(As + (m0 + mi * 16 + r16) * TLD + quad * 8);
#pragma unroll
    for (int ni = 0; ni < 4; ni++)
      bf[ni] = *(const half8*)(Bs + (ni * 16 + r16) * TLD + quad * 8);
#pragma unroll
    for (int mi = 0; mi < 2; mi++)
#pragma unroll
      for (int ni = 0; ni < 4; ni++)
        acc[mi][ni] = __builtin_amdgcn_mfma_f32_16x16x32_f16(af[mi], bf[ni], acc[mi][ni], 0, 0, 0);
  }
#pragma unroll
  for (int mi = 0; mi < 2; mi++)
#pragma unroll
    for (int ni = 0; ni < 4; ni++) {
      int d = ni * 16 + r16;
#pragma unroll
      for (int reg = 0; reg < 4; reg++) {
        int qrow = q0 + m0 + mi * 16 + quad * 4 + reg;
        AO[((size_t)(b * NSEQ + qrow)) * HIDDEN + h * HDIM + d] = (half_t)acc[mi][ni][reg];
      }
    }
}

// ---------------------------------------------------------------------------
// K5: out = AO @ Wo + bo, then zero masked query rows. fp32 out.
// ---------------------------------------------------------------------------
__global__ __launch_bounds__(256) void gemm_out_kernel(
    const half_t* __restrict__ AO, const half_t* __restrict__ WoT,
    const float* __restrict__ bo, const int* __restrict__ mask, float* __restrict__ out) {
  __shared__ half_t As[128 * TLD];
  __shared__ half_t Bs[128 * TLD];
  int row0 = blockIdx.x * 128, col0 = blockIdx.y * 128;
  f32x4 acc[4][4];
  gemm_core_128x128(AO + (size_t)row0 * HIDDEN, HIDDEN, WoT + (size_t)col0 * HIDDEN, HIDDEN,
                    HIDDEN, As, Bs, acc);
  int lane = threadIdx.x & 63, wave = threadIdx.x >> 6;
  int quad = lane >> 4, r16 = lane & 15;
  int m0 = (wave & 1) * 64, n0 = (wave >> 1) * 64;
#pragma unroll
  for (int mi = 0; mi < 4; mi++)
#pragma unroll
    for (int ni = 0; ni < 4; ni++) {
      int gcol = col0 + n0 + ni * 16 + r16;
      float bb = bo[gcol];
#pragma unroll
      for (int reg = 0; reg < 4; reg++) {
        int grow = row0 + m0 + mi * 16 + quad * 4 + reg;
        float v = acc[mi][ni][reg] + bb;
        out[(size_t)grow * HIDDEN + gcol] = mask[grow] ? v : 0.f;
      }
    }
}

// ---------------------------------------------------------------------------
extern "C" void kernel_launch(void* const* d_in, const int* in_sizes, int n_in,
                              void* d_out, int out_size, void* d_ws, size_t ws_size,
                              hipStream_t stream) {
  const float* x    = (const float*)d_in[0];
  const float* dist = (const float*)d_in[1];
  const int*   mask = (const int*)d_in[2];
  const float* Wq   = (const float*)d_in[3];
  const float* bq   = (const float*)d_in[4];
  const float* Wk   = (const float*)d_in[5];
  const float* bk   = (const float*)d_in[6];
  const float* Wv   = (const float*)d_in[7];
  const float* bv   = (const float*)d_in[8];
  const float* Wo   = (const float*)d_in[9];
  const float* bo   = (const float*)d_in[10];
  const float* Wd   = (const float*)d_in[11];
  const float* bd   = (const float*)d_in[12];
  float* out = (float*)d_out;

  char* ws = (char*)d_ws;
  size_t off = 0;
  auto take = [&](size_t bytes) {
    char* p = ws + off;
    off += (bytes + 255) & ~(size_t)255;
    return p;
  };
  half_t* xh  = (half_t*)take((size_t)NROWS * HIDDEN * 2);
  half_t* WqT = (half_t*)take((size_t)HIDDEN * HIDDEN * 2);
  half_t* WkT = (half_t*)take((size_t)HIDDEN * HIDDEN * 2);
  half_t* WvT = (half_t*)take((size_t)HIDDEN * HIDDEN * 2);
  half_t* WoT = (half_t*)take((size_t)HIDDEN * HIDDEN * 2);
  half_t* Qh  = (half_t*)take((size_t)NROWS * HIDDEN * 2);
  half_t* Kh  = (half_t*)take((size_t)NROWS * HIDDEN * 2);
  half_t* Vt  = (half_t*)take((size_t)NROWS * HIDDEN * 2);
  half_t* AO  = (half_t*)take((size_t)NROWS * HIDDEN * 2);
  half_t* S   = (half_t*)take((size_t)NB * NHEADS * NSEQ * NSEQ * 2);

  conv_x_kernel<<<(NROWS * HIDDEN) / (256 * 4), 256, 0, stream>>>(x, xh);
  conv_wt_kernel<<<dim3(8, 8, 4), 256, 0, stream>>>(Wq, Wk, Wv, Wo, WqT, WkT, WvT, WoT);
  gemm_qkv_kernel<<<dim3(32, 4, 3), 256, 0, stream>>>(xh, WqT, WkT, WvT, bq, bk, bv, Qh, Kh, Vt);
  gemm_scores_kernel<<<dim3(4, 4, 64), 256, 0, stream>>>(Qh, Kh, S);
  bias_softmax_kernel<<<dim3(NSEQ, NB), 256, 0, stream>>>(dist, Wd, bd, mask, S);
  gemm_pv_kernel<<<dim3(4, 1, 64), 256, 0, stream>>>(S, Vt, AO);
  gemm_out_kernel<<<dim3(32, 4), 256, 0, stream>>>(AO, WoT, bo, mask, out);
}